// Round 11
// baseline (218.590 us; speedup 1.0000x reference)
//
#include <hip/hip_runtime.h>
#include <hip/hip_bf16.h>
#include <stdint.h>

// B=4, S=8192, E=1024, heads=16 -> math collapses to:
//   Q = x @ W1[0:1024].T ; A = per-64-col-block softmax(Q/4) ; out = A @ W2.T
static constexpr int MTOT = 32768;
static constexpr int KD   = 1024;
static constexpr int ND   = 1024;

static constexpr int BM = 128, BN = 128, BK = 32;
static constexpr int NT = KD / BK;              // 32 K-tiles (even)
static constexpr int BUF_BYTES = 16384;         // per-buffer: A 8K + B 8K
static constexpr int BOFF = 8192;               // B offset within buffer

typedef __bf16 bf16x8 __attribute__((ext_vector_type(8)));
typedef float  f32x4  __attribute__((ext_vector_type(4)));

__device__ __forceinline__ unsigned short f2bf_rne(float f) {
  union { float f; uint32_t u; } c; c.f = f;
  uint32_t u = c.u;
  return (unsigned short)((u + 0x7fffu + ((u >> 16) & 1u)) >> 16);
}

__global__ void cast_f32_to_bf16(const float* __restrict__ src,
                                 unsigned short* __restrict__ dst, int n4) {
  int idx = blockIdx.x * blockDim.x + threadIdx.x;
  int stride = gridDim.x * blockDim.x;
  for (int i = idx; i < n4; i += stride) {
    float4 v = reinterpret_cast<const float4*>(src)[i];
    ushort4 o;
    o.x = f2bf_rne(v.x); o.y = f2bf_rne(v.y);
    o.z = f2bf_rne(v.z); o.w = f2bf_rne(v.w);
    reinterpret_cast<ushort4*>(dst)[i] = o;
  }
}

__device__ __forceinline__ void gload_lds16(const void* g, void* lds) {
  __builtin_amdgcn_global_load_lds(
      (const __attribute__((address_space(1))) unsigned int*)g,
      (__attribute__((address_space(3))) unsigned int*)lds, 16, 0, 0);
}

// r11: TLP-first. 128x128 tile, BK=32, 4 waves (2Mx2N, wave 64x64), 32 KiB
// LDS/block -> 4 blocks/CU = 16 waves/CU (2x the 256-sq config). Keeps all
// proven pieces: T1 XCD swizzle, T2 LDS swizzle (64B rows), depth-2 dbuf
// staging via global_load_lds, counted vmcnt(4) (never 0 in loop), 2
// barriers/K-tile, setprio, 16x16x32 MFMA. Hazards:
//  - reads of cur drained by lgkmcnt(0) BEFORE barrier#1 -> staging into cur
//    after barrier#1 is safe block-wide.
//  - vmcnt(4)+barrier#2 -> tile T+1 landed & visible before next iter reads.
//  - tail iters stage clamped tile NT-1 (duplicate content, same buffer
//    parity) to keep the vmcnt queue count exact; writes land after that
//    buffer's reads drained (same barrier proof), content irrelevant.
template <int SOFTMAX>
__global__ __launch_bounds__(256, 4)
void gemm4(const unsigned short* __restrict__ A,
           const unsigned short* __restrict__ Bm,
           void* __restrict__ Cout) {
  extern __shared__ __align__(16) char ldsc[];

  const int tid  = threadIdx.x;
  const int lane = tid & 63;
  const int wid  = tid >> 6;                   // 0..3
  const int wm = wid >> 1, wn = wid & 1;       // wave tile: 64 rows x 64 cols
  const int fr = lane & 15, fq = lane >> 4;

  // T1: bijective XCD swizzle (2048 blocks, 8 XCDs, 256 blocks/chunk).
  const int bid0 = blockIdx.x;
  const int bid  = ((bid0 & 7) << 8) | (bid0 >> 3);
  const int brow = (bid >> 3) * BM;            // 256 row tiles
  const int bcol = (bid & 7) * BN;             // 8 col tiles

  // Staging: linear LDS dest + inverse-swizzled global src (rule #21).
  // Unit = 128 rows x 32 bf16 cols (8KB) = 2 issues x 4KB; issue i, thread
  // tid -> LDS row i*64 + (tid>>2), slot tid&3 (16B slots, 64B rows).
  // Read-side swizzle f(r) = ((r>>1)&3) on the slot index -> source slot
  // gslot = (tid&3) ^ ((tid>>3)&3)  [since (srow>>1)&3 = (tid>>3)&3].
  const int srow  = tid >> 2;                  // 0..63
  const int gslot = (tid & 3) ^ ((tid >> 3) & 3);
  const unsigned short* gA = A  + (size_t)(brow + srow) * KD + gslot * 8;
  const unsigned short* gB = Bm + (size_t)(bcol + srow) * KD + gslot * 8;

  f32x4  acc[4][4] = {};
  bf16x8 a[4], b[4];

  auto STAGE = [&](const unsigned short* g, int kt, int bfp, int opOff) {
    #pragma unroll
    for (int i = 0; i < 2; ++i)
      gload_lds16(g + (size_t)(i * 64) * KD + kt * BK,
                  ldsc + bfp * BUF_BYTES + opOff + i * 4096 + tid * 16);
  };

  auto rdA = [&](int bfp) {
    const char* base = ldsc + bfp * BUF_BYTES;
    #pragma unroll
    for (int m = 0; m < 4; ++m) {
      const int r = wm * 64 + m * 16 + fr;
      a[m] = *(const bf16x8*)(base + (r << 6) +
                              ((fq << 4) ^ (((r >> 1) & 3) << 4)));
    }
  };
  auto rdB = [&](int bfp) {
    const char* base = ldsc + bfp * BUF_BYTES + BOFF;
    #pragma unroll
    for (int n = 0; n < 4; ++n) {
      const int r = wn * 64 + n * 16 + fr;
      b[n] = *(const bf16x8*)(base + (r << 6) +
                              ((fq << 4) ^ (((r >> 1) & 3) << 4)));
    }
  };

  // --- prologue: tiles 0,1 -> bufs 0,1 (8 loads) ---
  STAGE(gA, 0, 0, 0); STAGE(gB, 0, 0, BOFF);
  STAGE(gA, 1, 1, 0); STAGE(gB, 1, 1, BOFF);
  asm volatile("s_waitcnt vmcnt(4)" ::: "memory");   // tile0 landed; tile1 in flight
  __builtin_amdgcn_s_barrier();

  #pragma unroll 2
  for (int T = 0; T < NT; ++T) {
    const int cur = T & 1;
    const int tp2 = (T + 2 < NT) ? T + 2 : NT - 1;

    rdA(cur); rdB(cur);                              // 8 ds_read_b128
    asm volatile("s_waitcnt lgkmcnt(0)" ::: "memory");
    __builtin_amdgcn_s_barrier();                    // all waves' cur reads done

    STAGE(gA, tp2, cur, 0);                          // depth-2 prefetch -> cur
    STAGE(gB, tp2, cur, BOFF);

    __builtin_amdgcn_s_setprio(1);
    #pragma unroll
    for (int m = 0; m < 4; ++m)
      #pragma unroll
      for (int n = 0; n < 4; ++n)
        acc[m][n] = __builtin_amdgcn_mfma_f32_16x16x32_bf16(
            a[m], b[n], acc[m][n], 0, 0, 0);
    __builtin_amdgcn_s_setprio(0);

    // queue: [T+1 x4, T+2 x4] -> retire T+1, keep T+2 in flight (never 0)
    asm volatile("s_waitcnt vmcnt(4)" ::: "memory");
    __builtin_amdgcn_s_barrier();                    // tile T+1 visible to all
  }

  if constexpr (SOFTMAX) {
    // logits = acc/4; softmax over the wave's 64-col block (= one head block)
    unsigned short* attn = reinterpret_cast<unsigned short*>(Cout);
    constexpr float CEXP = 0.25f * 1.44269504088896340736f; // log2(e)/4
    #pragma unroll
    for (int m = 0; m < 4; ++m) {
      const int row = brow + wm * 64 + m * 16 + fq * 4;
      #pragma unroll
      for (int j = 0; j < 4; ++j) {
        float v0 = acc[m][0][j], v1 = acc[m][1][j];
        float v2 = acc[m][2][j], v3 = acc[m][3][j];
        float mx = fmaxf(fmaxf(v0, v1), fmaxf(v2, v3));
        #pragma unroll
        for (int s = 1; s < 16; s <<= 1) mx = fmaxf(mx, __shfl_xor(mx, s, 64));
        float p0 = exp2f((v0 - mx) * CEXP);
        float p1 = exp2f((v1 - mx) * CEXP);
        float p2 = exp2f((v2 - mx) * CEXP);
        float p3 = exp2f((v3 - mx) * CEXP);
        float sm = p0 + p1 + p2 + p3;
        #pragma unroll
        for (int s = 1; s < 16; s <<= 1) sm += __shfl_xor(sm, s, 64);
        const float inv = 1.0f / sm;
        unsigned short* dst =
            attn + (size_t)(row + j) * ND + (bcol + wn * 64 + fr);
        dst[0]  = f2bf_rne(p0 * inv);
        dst[16] = f2bf_rne(p1 * inv);
        dst[32] = f2bf_rne(p2 * inv);
        dst[48] = f2bf_rne(p3 * inv);
      }
    }
  } else {
    float* Cf = reinterpret_cast<float*>(Cout);
    #pragma unroll
    for (int m = 0; m < 4; ++m) {
      const int row = brow + wm * 64 + m * 16 + fq * 4;
      #pragma unroll
      for (int n = 0; n < 4; ++n) {
        const int col = bcol + wn * 64 + n * 16 + fr;
        #pragma unroll
        for (int j = 0; j < 4; ++j)
          Cf[(size_t)(row + j) * ND + col] = acc[m][n][j];
      }
    }
  }
}

extern "C" void kernel_launch(void* const* d_in, const int* in_sizes, int n_in,
                              void* d_out, int out_size, void* d_ws, size_t ws_size,
                              hipStream_t stream) {
  const float* x  = (const float*)d_in[0];   // [4,8192,1024] f32
  const float* W1 = (const float*)d_in[1];   // [3072,1024]  f32 (rows 0..1023 = Wq)
  const float* W2 = (const float*)d_in[2];   // [1024,1024]  f32
  float* out = (float*)d_out;

  char* ws = (char*)d_ws;
  unsigned short* xb   = (unsigned short*)(ws);
  unsigned short* w1b  = (unsigned short*)(ws + (size_t)67108864);
  unsigned short* w2b  = (unsigned short*)(ws + (size_t)69206016);
  unsigned short* attn = (unsigned short*)(ws + (size_t)71303168);

  hipFuncSetAttribute(reinterpret_cast<const void*>(gemm4<1>),
                      hipFuncAttributeMaxDynamicSharedMemorySize, 32768);
  hipFuncSetAttribute(reinterpret_cast<const void*>(gemm4<0>),
                      hipFuncAttributeMaxDynamicSharedMemorySize, 32768);

  cast_f32_to_bf16<<<2048, 256, 0, stream>>>(x,  xb,  MTOT * KD / 4);
  cast_f32_to_bf16<<<512,  256, 0, stream>>>(W1, w1b, KD * KD / 4);
  cast_f32_to_bf16<<<512,  256, 0, stream>>>(W2, w2b, KD * KD / 4);

  const int nblk = (MTOT / BM) * (ND / BN);   // 256 * 8 = 2048
  gemm4<1><<<nblk, 256, 32768, stream>>>(xb, w1b, (void*)attn);
  gemm4<0><<<nblk, 256, 32768, stream>>>(attn, w2b, (void*)out);
}